// Round 5
// baseline (73.552 us; speedup 1.0000x reference)
//
#include <hip/hip_runtime.h>

// ConvCapsules2d: V[b,i,c,d,f,g,k,l] = (sum_p poses[b,i,p,2f+k,2g+l]) * W[i,c,d,k,l]
// poses (16,32,16,14,14) f32, W (32,32,16,3,3) f32
// out (16,32,32,16,6,6,3,3) f32 = 84,934,656 elems = 339.7 MB -> HBM-write-bound.
//
// R5: two-kernel split.
//  A: s[bi][e] = sum_p poses[...]  -> d_ws (512*324 floats = 663,552 B)
//  B: pure grid-stride stream expander (fill-kernel-shaped): no LDS, no
//     syncthreads, no prologue. flat float4 q index fq:
//       fq = (bi*512 + cd)*81 + j,  e0 = 4*j
//       out[fq*4 ..] = s[bi*324 + e0 ..] * W[(i*512+cd)*9 + kl(e0..e0+3)]
//     store addr = fq*16B -> perfectly contiguous per wave.

#define N_BATCH 16
#define B_IN    32
#define P_DIM   16
#define H_IN    14
#define C_OUT   32
#define D_OUT   16

typedef float f32x4 __attribute__((ext_vector_type(4)));

#define S_ELEMS   324                         // 6*6*3*3 per (b,i) panel
#define N_BI      (N_BATCH * B_IN)            // 512
#define S_TOTAL   (N_BI * S_ELEMS)            // 165,888 floats
#define TOTAL4    (N_BI * C_OUT * D_OUT * (S_ELEMS / 4))   // 21,233,664 float4s

// ---------------- kernel A: reduce poses -> s ----------------
__global__ __launch_bounds__(256)
void s_reduce_kernel(const float* __restrict__ poses, float* __restrict__ s)
{
    const int bi  = blockIdx.x;                // 0..511
    const int tid = threadIdx.x;
    const float* pb = poses + (size_t)bi * (P_DIM * H_IN * H_IN);

    for (int e = tid; e < S_ELEMS; e += 256) {
        int f  = e / 54;
        int r  = e - f * 54;
        int g  = r / 9;
        int kl = r - g * 9;
        int k  = kl / 3;
        int l  = kl - k * 3;
        const float* p0 = pb + (2 * f + k) * H_IN + (2 * g + l);
        float acc = 0.f;
        #pragma unroll
        for (int p = 0; p < P_DIM; ++p) acc += p0[p * (H_IN * H_IN)];
        s[bi * S_ELEMS + e] = acc;
    }
}

// ---------------- kernel B: pure streaming expansion ----------------
__global__ __launch_bounds__(256)
void expand_kernel(const float* __restrict__ s,
                   const float* __restrict__ W,
                   float* __restrict__ out)
{
    const unsigned stride = gridDim.x * 256u;
    for (unsigned fq = blockIdx.x * 256u + threadIdx.x; fq < (unsigned)TOTAL4; fq += stride) {
        unsigned t  = fq / 81u;             // = bi*512 + cd   (magic-mul)
        unsigned j  = fq - t * 81u;         // quad within panel, 0..80
        unsigned cd = t & 511u;             // c*16 + d
        unsigned bi = t >> 9;               // b*32 + i
        unsigned i  = bi & 31u;
        unsigned e0 = j * 4u;               // element 0..320
        unsigned kl0 = e0 % 9u;
        unsigned kl1 = kl0 + 1u; if (kl1 == 9u) kl1 = 0u;
        unsigned kl2 = kl1 + 1u; if (kl2 == 9u) kl2 = 0u;
        unsigned kl3 = kl2 + 1u; if (kl3 == 9u) kl3 = 0u;

        const f32x4 s4 = *(const f32x4*)(s + bi * S_ELEMS + e0);   // 16B aligned, coalesced
        const float* wr = W + ((size_t)i * 512u + cd) * 9u;        // L2-resident

        f32x4 v;
        v.x = s4.x * wr[kl0];
        v.y = s4.y * wr[kl1];
        v.z = s4.z * wr[kl2];
        v.w = s4.w * wr[kl3];
        *(f32x4*)(out + (size_t)fq * 4u) = v;                      // contiguous stream
    }
}

// ---------------- fallback: R4 single-kernel (73.0 us) ----------------
#define CQ      8
#define W_ELEMS (CQ * D_OUT * 9)
#define V4_PER_BLOCK (CQ * D_OUT * (S_ELEMS/4))

__global__ __launch_bounds__(256)
void convcaps_fallback(const float* __restrict__ poses,
                       const float* __restrict__ W,
                       float* __restrict__ out)
{
    __shared__ float s_lds[S_ELEMS];
    __shared__ float w_lds[W_ELEMS];

    const int tid = threadIdx.x;
    const int blk = blockIdx.x;
    const int cq  = blk & 3;
    const int bi  = blk >> 2;
    const int i   = bi & (B_IN - 1);
    const int b   = bi >> 5;
    const int c0  = cq * CQ;

    for (int e = tid; e < S_ELEMS; e += 256) {
        int f  = e / 54;
        int r  = e - f * 54;
        int g  = r / 9;
        int kl = r - g * 9;
        int k  = kl / 3;
        int l  = kl - k * 3;
        const float* p0 = poses
            + (size_t)(b * B_IN + i) * (P_DIM * H_IN * H_IN)
            + (2 * f + k) * H_IN + (2 * g + l);
        float acc = 0.f;
        #pragma unroll
        for (int p = 0; p < P_DIM; ++p) acc += p0[p * (H_IN * H_IN)];
        s_lds[e] = acc;
    }
    {
        const float* wsrc = W + (size_t)(i * C_OUT + c0) * (D_OUT * 9);
        for (int j = tid; j < W_ELEMS; j += 256) w_lds[j] = wsrc[j];
    }
    __syncthreads();

    float* obase = out + (size_t)((b * B_IN + i) * C_OUT + c0) * (D_OUT * S_ELEMS);
    for (int idx = tid; idx < V4_PER_BLOCK; idx += 256) {
        int cd = idx / 81;
        int q  = idx - cd * 81;
        int e  = q * 4;
        const float* wrow = &w_lds[cd * 9];
        f32x4 v;
        int kl0 = (e + 0) % 9;
        int kl1 = (e + 1) % 9;
        int kl2 = (e + 2) % 9;
        int kl3 = (e + 3) % 9;
        v.x = s_lds[e + 0] * wrow[kl0];
        v.y = s_lds[e + 1] * wrow[kl1];
        v.z = s_lds[e + 2] * wrow[kl2];
        v.w = s_lds[e + 3] * wrow[kl3];
        *(f32x4*)(obase + (size_t)cd * S_ELEMS + e) = v;
    }
}

extern "C" void kernel_launch(void* const* d_in, const int* in_sizes, int n_in,
                              void* d_out, int out_size, void* d_ws, size_t ws_size,
                              hipStream_t stream) {
    const float* poses = (const float*)d_in[0];
    const float* W     = (const float*)d_in[1];
    float* out         = (float*)d_out;

    if (ws_size >= (size_t)S_TOTAL * sizeof(float)) {
        float* s = (float*)d_ws;
        s_reduce_kernel<<<N_BI, 256, 0, stream>>>(poses, s);
        expand_kernel<<<4096, 256, 0, stream>>>(s, W, out);
    } else {
        const int grid = N_BATCH * B_IN * (C_OUT / CQ);   // 2048
        convcaps_fallback<<<grid, 256, 0, stream>>>(poses, W, out);
    }
}

// Round 6
// 72.933 us; speedup vs baseline: 1.0085x; 1.0085x over previous
//
#include <hip/hip_runtime.h>

// ConvCapsules2d: V[b,i,c,d,f,g,k,l] = (sum_p poses[b,i,p,2f+k,2g+l]) * W[i,c,d,k,l]
// poses (16,32,16,14,14) f32, W (32,32,16,3,3) f32
// out (16,32,32,16,6,6,3,3) f32 = 84,934,656 elems = 339.7 MB -> HBM-write-bound.
//
// R6: fused single kernel, minimal in-loop work:
//  - s quad via ONE ds_read_b128 (consecutive 16B chunks -> ~2-way, free)
//  - W rows duplicated 9->12 floats in LDS: reads are wr[kl0..kl0+3], no wrap
//  - incremental index decode (no div/mod in loop): idx+=256 == {cd+=3,q+=13}
//    with wrap; kl0 += 7 (52 mod 9), invariant under q-wrap (324 = 36*9)
//  - stores: regular (non-NT) dwordx4, block output fully contiguous

#define N_BATCH 16
#define B_IN    32
#define P_DIM   16
#define H_IN    14
#define C_OUT   32
#define D_OUT   16

#define S_ELEMS 324                  // 6*6*3*3 panel
#define CQ      8                    // c's per block
#define NCD     (CQ * D_OUT)         // 128 (c,d) panels per block
#define W12     (NCD * 12)           // duplicated W rows: 1536 floats
#define V4PB    (NCD * (S_ELEMS/4))  // 10368 float4 per block

typedef float f32x4 __attribute__((ext_vector_type(4)));

__global__ __launch_bounds__(256)
void convcaps_kernel(const float* __restrict__ poses,
                     const float* __restrict__ W,
                     float* __restrict__ out)
{
    __shared__ float s_lds[S_ELEMS];
    __shared__ float w_lds[W12];     // w_lds[cd*12 + t] = W[cd*9 + t%9], t<12

    const int tid = threadIdx.x;
    const int blk = blockIdx.x;      // 0..2047
    const int cq  = blk & 3;
    const int bi  = blk >> 2;        // b*32 + i
    const int i   = bi & (B_IN - 1);
    const int c0  = cq * CQ;

    // ---- stage 1: s[e] = sum_p poses[b,i,p,2f+k,2g+l], e = ((f*6+g)*3+k)*3+l
    for (int e = tid; e < S_ELEMS; e += 256) {
        int f  = e / 54;
        int r  = e - f * 54;
        int g  = r / 9;
        int kl = r - g * 9;
        int k  = kl / 3;
        int l  = kl - k * 3;
        const float* p0 = poses
            + (size_t)bi * (P_DIM * H_IN * H_IN)
            + (2 * f + k) * H_IN + (2 * g + l);
        float acc = 0.f;
        #pragma unroll
        for (int p = 0; p < P_DIM; ++p) acc += p0[p * (H_IN * H_IN)];
        s_lds[e] = acc;
    }

    // ---- stage 2: W[i, c0..c0+7, :, :, :] (1152 floats) -> 12-wide rows
    {
        const float* wsrc = W + (size_t)(i * C_OUT + c0) * (D_OUT * 9);
        for (int j = tid; j < W12; j += 256) {
            int cd = j / 12;
            int t  = j - cd * 12;
            int st = (t >= 9) ? (t - 9) : t;
            w_lds[j] = wsrc[cd * 9 + st];
        }
    }
    __syncthreads();

    // ---- stage 3: stream 10368 float4 per block, incremental decode
    // per-thread init: idx = tid -> cd = tid/81, q = tid%81, kl0 = (4q)%9
    int cd0  = tid / 81;                    // 0..3 (compiler magic-mul, once)
    int q    = tid - cd0 * 81;              // 0..80
    int kl0  = (q * 4) % 9;                 // once
    int woff = cd0 * 12;

    f32x4* optr = (f32x4*)(out
        + (size_t)(bi * C_OUT + c0) * (D_OUT * S_ELEMS))
        + tid;

    for (int idx = tid; idx < V4PB; idx += 256) {
        const f32x4 s4 = *(const f32x4*)&s_lds[q * 4];     // one ds_read_b128
        const float* wr = &w_lds[woff + kl0];              // 4-float window, no wrap
        f32x4 v;
        v.x = s4.x * wr[0];
        v.y = s4.y * wr[1];
        v.z = s4.z * wr[2];
        v.w = s4.w * wr[3];
        *optr = v;

        optr += 256;
        q    += 13;                 // 256 = 3*81 + 13
        kl0  += 7;                  // 4*13 = 52 ≡ 7 (mod 9); q-wrap is ≡0 (mod 9)
        woff += 36;                 // 3 panels * 12
        if (q   >= 81) { q -= 81; woff += 12; }
        if (kl0 >= 9)  { kl0 -= 9; }
    }
}

extern "C" void kernel_launch(void* const* d_in, const int* in_sizes, int n_in,
                              void* d_out, int out_size, void* d_ws, size_t ws_size,
                              hipStream_t stream) {
    const float* poses = (const float*)d_in[0];
    const float* W     = (const float*)d_in[1];
    float* out         = (float*)d_out;

    const int grid = N_BATCH * B_IN * (C_OUT / CQ);   // 2048 = 8 blocks/CU
    convcaps_kernel<<<grid, 256, 0, stream>>>(poses, W, out);
}